// Round 2
// baseline (100.337 us; speedup 1.0000x reference)
//
#include <hip/hip_runtime.h>
#include <stdint.h>

typedef _Float16 half4 __attribute__((ext_vector_type(4)));
typedef _Float16 half8 __attribute__((ext_vector_type(8)));
typedef float f32x4 __attribute__((ext_vector_type(4)));

#define NS 4096
#define NTOT 8192
#define DD 256
#define NBLK 2080   // 528 SS lower-tri + 528 TT lower-tri + 1024 ST full

// workspace layout (bytes)
#define OFF_X16   0                        // 8192*256*2 = 4 MB fp16
#define OFF_SQ    (4*1024*1024)            // 8192 floats (32 KB)
#define OFF_BP    (OFF_SQ + 32*1024)       // 2080 floats
#define OFF_SCAL  (OFF_BP + 8320)          // 1 float (exp2 scale)
#define OFF_ATOM  (OFF_SQ + 48*1024)       // int64 colsum[256] | int64 sqsum | int ctr1 | int ctr2

#define FIXSCALE 16777216.0   // 2^24 fixed-point for deterministic atomics

// ---------------------------------------------------------------- K1: prep + bandwidth
// 256 blocks x 256 threads (4 waves). Block b handles rows [32b, 32b+32),
// one row per wave per iteration; lane l owns cols [4l, 4l+4).
// Produces fp16 copy, per-row sq, and (via deterministic fixed-point atomics)
// global column sums + global sum of squares; the LAST block computes the
// exp2 bandwidth scale.
__global__ __launch_bounds__(256) void mmd_prep(const float* __restrict__ S,
                                                const float* __restrict__ T,
                                                _Float16* __restrict__ X16,
                                                float* __restrict__ sq,
                                                long long* __restrict__ colsum,
                                                long long* __restrict__ sqsum,
                                                int* __restrict__ ctr,
                                                float* __restrict__ scal) {
    __shared__ float cl[4][256];
    __shared__ float wq[4];
    __shared__ int amLast;
    __shared__ double sd[4];
    const int b = blockIdx.x, tid = threadIdx.x;
    const int lane = tid & 63, w = tid >> 6;

    f32x4 cacc = {0.f, 0.f, 0.f, 0.f};
    float myq = 0.f;
    #pragma unroll
    for (int it = 0; it < 8; ++it) {
        const int row = b * 32 + it * 4 + w;
        const float* src = (row < NS) ? (S + (size_t)row * DD)
                                      : (T + (size_t)(row - NS) * DD);
        const f32x4 v = *(const f32x4*)(src + lane * 4);
        cacc += v;
        float vv = v.x * v.x + v.y * v.y + v.z * v.z + v.w * v.w;
        myq += vv;
        half4 h = { (_Float16)v.x, (_Float16)v.y, (_Float16)v.z, (_Float16)v.w };
        *(half4*)(X16 + (size_t)row * DD + lane * 4) = h;
        #pragma unroll
        for (int off = 32; off; off >>= 1) vv += __shfl_down(vv, off);
        if (lane == 0) sq[row] = vv;
    }

    // block-level column partials -> one fixed-point atomic per column
    *(f32x4*)&cl[w][lane * 4] = cacc;
    #pragma unroll
    for (int off = 32; off; off >>= 1) myq += __shfl_down(myq, off);
    if (lane == 0) wq[w] = myq;
    __syncthreads();
    const float cs = cl[0][tid] + cl[1][tid] + cl[2][tid] + cl[3][tid];
    atomicAdd((unsigned long long*)&colsum[tid],
              (unsigned long long)(long long)llrintf(cs * (float)FIXSCALE));
    if (tid == 0) {
        const double q = (double)wq[0] + wq[1] + wq[2] + wq[3];
        atomicAdd((unsigned long long*)sqsum,
                  (unsigned long long)(long long)(q * FIXSCALE));
    }
    __threadfence();
    __syncthreads();
    if (tid == 0) amLast = (atomicAdd(ctr, 1) == gridDim.x - 1) ? 1 : 0;
    __syncthreads();
    if (amLast) {
        __threadfence();
        const long long cv = (long long)atomicAdd((unsigned long long*)&colsum[tid], 0ull);
        const double c = (double)cv * (1.0 / FIXSCALE);
        double s2 = c * c;
        #pragma unroll
        for (int off = 32; off; off >>= 1) s2 += __shfl_down(s2, off);
        if (lane == 0) sd[w] = s2;
        __syncthreads();
        if (tid == 0) {
            const long long qv = (long long)atomicAdd((unsigned long long*)sqsum, 0ull);
            const double qt = (double)qv * (1.0 / FIXSCALE);
            const double s2t = sd[0] + sd[1] + sd[2] + sd[3];
            const double n = (double)NTOT;
            const double sumd2 = 2.0 * n * qt - 2.0 * s2t;  // clamp term negligible
            double bwv = sumd2 / (n * n - n);
            bwv = bwv / 4.0;   // KERNEL_MUL^(KERNEL_NUM//2) = 2^2
            // e4 = exp(-d2/(16*bw)) = exp2(-d2 * cl2)
            scal[0] = (float)(1.0 / (16.0 * bwv * 0.6931471805599453));
        }
    }
}

// ---------------------------------------------------------------- K3: main GEMM+kernel
// 128x128 tile, BK=64, 4 waves (2x2 of 64x64), fp16 16x16x32 MFMA,
// global_load_lds width-16 staging, fused exp epilogue; LAST block does the
// deterministic final reduction and writes the loss.
__global__ __launch_bounds__(256) void mmd_main(const _Float16* __restrict__ X16,
                                                const float* __restrict__ sq,
                                                const float* __restrict__ scal,
                                                float* __restrict__ blockpart,
                                                int* __restrict__ ctr,
                                                float* __restrict__ out) {
    __shared__ _Float16 As[128 * 64];
    __shared__ _Float16 Bs[128 * 64];
    __shared__ float wsum[4];
    __shared__ int lastFlag;
    __shared__ double sd2[4];

    const int bid = blockIdx.x;
    int br, bc;
    float wfac;
    if (bid < 1056) {
        int t = bid, base = 0;
        if (t >= 528) { t -= 528; base = 32; }
        int i = (int)((sqrtf(8.0f * (float)t + 1.0f) - 1.0f) * 0.5f);
        while ((i + 1) * (i + 2) / 2 <= t) ++i;
        while (i * (i + 1) / 2 > t) --i;
        const int j = t - i * (i + 1) / 2;
        br = base + i; bc = base + j;
        wfac = (i == j) ? 1.0f : 2.0f;   // off-diag tile counts for (i,j) and (j,i)
    } else {
        const int t = bid - 1056;
        br = t >> 5; bc = 32 + (t & 31);
        wfac = -2.0f;                    // loss has -2*xy
    }
    const int row0 = br * 128, col0 = bc * 128;
    const int tid = threadIdx.x;
    const int lane = tid & 63;
    const int w = tid >> 6;
    const int wr = (w >> 1) * 64, wc = (w & 1) * 64;

    f32x4 acc[4][4] = {};

    const int rA = lane & 15, kof = (lane >> 4) * 8;

    for (int kt = 0; kt < 4; ++kt) {
        const int k0 = kt * 64;
        #pragma unroll
        for (int p = 0; p < 4; ++p) {
            const int chunk = p * 256 + tid;           // 0..1023, 16B each
            const int r = chunk >> 3, cb = chunk & 7;
            const _Float16* ga = X16 + (size_t)(row0 + r) * DD + k0 + cb * 8;
            const _Float16* gb = X16 + (size_t)(col0 + r) * DD + k0 + cb * 8;
            __builtin_amdgcn_global_load_lds(
                (const __attribute__((address_space(1))) uint32_t*)ga,
                (__attribute__((address_space(3))) uint32_t*)&As[chunk * 8], 16, 0, 0);
            __builtin_amdgcn_global_load_lds(
                (const __attribute__((address_space(1))) uint32_t*)gb,
                (__attribute__((address_space(3))) uint32_t*)&Bs[chunk * 8], 16, 0, 0);
        }
        __syncthreads();
        #pragma unroll
        for (int ks = 0; ks < 64; ks += 32) {
            half8 a[4], b[4];
            #pragma unroll
            for (int m = 0; m < 4; ++m)
                a[m] = *(const half8*)&As[(wr + m * 16 + rA) * 64 + ks + kof];
            #pragma unroll
            for (int n = 0; n < 4; ++n)
                b[n] = *(const half8*)&Bs[(wc + n * 16 + rA) * 64 + ks + kof];
            #pragma unroll
            for (int m = 0; m < 4; ++m)
                #pragma unroll
                for (int n = 0; n < 4; ++n)
                    acc[m][n] = __builtin_amdgcn_mfma_f32_16x16x32_f16(
                        a[m], b[n], acc[m][n], 0, 0, 0);
        }
        __syncthreads();
    }

    // epilogue: d2 -> 5-bandwidth kernel sum via e4 = exp2(-d2*cl2), powers 1,2,4,8,16
    const float cl2 = scal[0];
    const int c_lo = lane & 15, r_hi = lane >> 4;
    float sj[4], si[4][4];
    #pragma unroll
    for (int n = 0; n < 4; ++n) sj[n] = sq[col0 + wc + n * 16 + c_lo];
    #pragma unroll
    for (int m = 0; m < 4; ++m)
        #pragma unroll
        for (int r = 0; r < 4; ++r) si[m][r] = sq[row0 + wr + m * 16 + r_hi * 4 + r];

    float part = 0.0f;
    #pragma unroll
    for (int m = 0; m < 4; ++m)
        #pragma unroll
        for (int n = 0; n < 4; ++n)
            #pragma unroll
            for (int r = 0; r < 4; ++r) {
                const float g = acc[m][n][r];
                const float d2v = fmaxf(si[m][r] + sj[n] - 2.0f * g, 0.0f);
                float e = exp2f(-d2v * cl2);
                float ksum = e;
                e *= e; ksum += e;   // ^2
                e *= e; ksum += e;   // ^4
                e *= e; ksum += e;   // ^8
                e *= e; ksum += e;   // ^16
                part += ksum;
            }

    #pragma unroll
    for (int off = 32; off > 0; off >>= 1) part += __shfl_down(part, off);
    if (lane == 0) wsum[w] = part;
    __syncthreads();
    if (tid == 0) {
        blockpart[bid] = (wsum[0] + wsum[1] + wsum[2] + wsum[3]) * wfac;
        __threadfence();
        lastFlag = (atomicAdd(ctr, 1) == NBLK - 1) ? 1 : 0;
    }
    __syncthreads();
    if (lastFlag) {
        __threadfence();
        double a = 0.0;
        for (int i = tid; i < NBLK; i += 256) a += (double)blockpart[i];
        #pragma unroll
        for (int off = 32; off > 0; off >>= 1) a += __shfl_down(a, off);
        if (lane == 0) sd2[w] = a;
        __syncthreads();
        if (tid == 0) {
            const double tot = (sd2[0] + sd2[1] + sd2[2] + sd2[3]) /
                               ((double)NS * (double)NS);
            out[0] = (float)fmax(tot, 0.0);
        }
    }
}

// ---------------------------------------------------------------- launch
extern "C" void kernel_launch(void* const* d_in, const int* in_sizes, int n_in,
                              void* d_out, int out_size, void* d_ws, size_t ws_size,
                              hipStream_t stream) {
    const float* S = (const float*)d_in[0];
    const float* T = (const float*)d_in[1];
    char* ws = (char*)d_ws;
    _Float16* X16    = (_Float16*)(ws + OFF_X16);
    float* sq        = (float*)(ws + OFF_SQ);
    float* blockpart = (float*)(ws + OFF_BP);
    float* scal      = (float*)(ws + OFF_SCAL);
    long long* colsum = (long long*)(ws + OFF_ATOM);
    long long* sqsum  = (long long*)(ws + OFF_ATOM + 2048);
    int* ctr1 = (int*)(ws + OFF_ATOM + 2056);
    int* ctr2 = (int*)(ws + OFF_ATOM + 2060);

    hipMemsetAsync(ws + OFF_ATOM, 0, 2064, stream);
    mmd_prep<<<256, 256, 0, stream>>>(S, T, X16, sq, colsum, sqsum, ctr1, scal);
    mmd_main<<<NBLK, 256, 0, stream>>>(X16, sq, scal, blockpart, ctr2, (float*)d_out);
}

// Round 3
// 69.763 us; speedup vs baseline: 1.4383x; 1.4383x over previous
//
#include <hip/hip_runtime.h>
#include <stdint.h>

typedef _Float16 half8 __attribute__((ext_vector_type(8)));
typedef float f32x4 __attribute__((ext_vector_type(4)));

#define NS 4096
#define NTOT 8192
#define DD 256
#define NBLK 2080   // 528 SS lower-tri + 528 TT lower-tri + 1024 ST full

// workspace layout (bytes)
#define OFF_X16   0                        // 8192*256*2 = 4 MB fp16
#define OFF_SQ    (4*1024*1024)            // 8192 floats
#define OFF_COLP  (OFF_SQ + 32*1024)       // 256*256 floats = 256 KB
#define OFF_BP    (OFF_COLP + 256*1024)    // 2080 floats
#define OFF_SCAL  (OFF_BP + 2080*4)        // 1 float (exp2 scale)

// ---------------------------------------------------------------- K1: prep
// 256 blocks x 256 threads; block b handles rows [32b, 32b+32).
// Writes fp16 copy, per-row sq, per-block column-sum partials.
__global__ __launch_bounds__(256) void mmd_prep(const float* __restrict__ S,
                                                const float* __restrict__ T,
                                                _Float16* __restrict__ X16,
                                                float* __restrict__ sq,
                                                float* __restrict__ colpart) {
    __shared__ float wpart[32 * 4];
    const int b = blockIdx.x, t = threadIdx.x;
    const int lane = t & 63, w = t >> 6;
    float cacc = 0.0f;
    for (int r = 0; r < 32; ++r) {
        const int row = b * 32 + r;
        const float* src = (row < NS) ? (S + (size_t)row * DD)
                                      : (T + (size_t)(row - NS) * DD);
        const float v = src[t];
        cacc += v;
        X16[(size_t)row * DD + t] = (_Float16)v;
        float vv = v * v;
        #pragma unroll
        for (int off = 32; off > 0; off >>= 1) vv += __shfl_down(vv, off);
        if (lane == 0) wpart[r * 4 + w] = vv;
    }
    __syncthreads();
    if (t < 32) sq[b * 32 + t] = wpart[t * 4 + 0] + wpart[t * 4 + 1] +
                                 wpart[t * 4 + 2] + wpart[t * 4 + 3];
    colpart[b * 256 + t] = cacc;
}

// ---------------------------------------------------------------- K2: bandwidth
// 1 block, 256 threads. sum(d2) = 2*n*sum(sq) - 2*||colsum||^2 (clamp negligible).
__global__ __launch_bounds__(256) void mmd_bw(const float* __restrict__ colpart,
                                              const float* __restrict__ sq,
                                              float* __restrict__ scal) {
    const int t = threadIdx.x;
    float cs = 0.0f;
    for (int b = 0; b < 256; ++b) cs += colpart[b * 256 + t];
    double s2 = (double)cs * (double)cs;
    float qs = 0.0f;
    for (int k = 0; k < 32; ++k) qs += sq[t + 256 * k];
    double qd = (double)qs;
    #pragma unroll
    for (int off = 32; off > 0; off >>= 1) {
        s2 += __shfl_down(s2, off);
        qd += __shfl_down(qd, off);
    }
    __shared__ double sd[4], sf[4];
    const int lane = t & 63, w = t >> 6;
    if (lane == 0) { sd[w] = s2; sf[w] = qd; }
    __syncthreads();
    if (t == 0) {
        const double s2t = sd[0] + sd[1] + sd[2] + sd[3];
        const double qt  = sf[0] + sf[1] + sf[2] + sf[3];
        const double sumd2 = 2.0 * (double)NTOT * qt - 2.0 * s2t;
        const double n = (double)NTOT;
        double bwv = sumd2 / (n * n - n);
        bwv = bwv / 4.0;   // KERNEL_MUL^(KERNEL_NUM//2) = 2^2
        // e4 = exp(-d2/(16*bw)) = exp2(-d2 * cl2)
        scal[0] = (float)(1.0 / (16.0 * bwv * 0.6931471805599453));
    }
}

// ---------------------------------------------------------------- K3: main GEMM+kernel
// 128x128 tile, BK=64, 4 waves (2x2 of 64x64), fp16 16x16x32 MFMA.
// T2 XOR-swizzled LDS (rule 21: linear global_load_lds dest + pre-swizzled
// global source + swizzled ds_read) to kill the 16-way bank conflict of
// the 128B-stride row-major tile. Fused exp epilogue.
__global__ __launch_bounds__(256, 4) void mmd_main(const _Float16* __restrict__ X16,
                                                   const float* __restrict__ sq,
                                                   const float* __restrict__ scal,
                                                   float* __restrict__ blockpart) {
    __shared__ _Float16 As[128 * 64];
    __shared__ _Float16 Bs[128 * 64];

    const int bid = blockIdx.x;
    int br, bc;
    float wfac;
    if (bid < 1056) {
        int t = bid, base = 0;
        if (t >= 528) { t -= 528; base = 32; }
        int i = (int)((sqrtf(8.0f * (float)t + 1.0f) - 1.0f) * 0.5f);
        while ((i + 1) * (i + 2) / 2 <= t) ++i;
        while (i * (i + 1) / 2 > t) --i;
        const int j = t - i * (i + 1) / 2;
        br = base + i; bc = base + j;
        wfac = (i == j) ? 1.0f : 2.0f;   // off-diag tile counts for (i,j) and (j,i)
    } else {
        const int t = bid - 1056;
        br = t >> 5; bc = 32 + (t & 31);
        wfac = -2.0f;                    // loss has -2*xy
    }
    const int row0 = br * 128, col0 = bc * 128;
    const int tid = threadIdx.x;
    const int lane = tid & 63;
    const int w = tid >> 6;
    const int wr = (w >> 1) * 64, wc = (w & 1) * 64;

    f32x4 acc[4][4] = {};

    const int rA = lane & 15;
    const int hi = lane >> 4;            // 0..3 -> k-chunk offset within 32-wide slice
    const int swz = rA & 7;              // row&7 is lane-uniform across m/n fragments

    // staging decomposition: chunk = p*256+tid -> (r = chunk>>3, cb = chunk&7)
    const int st_r  = tid >> 3;          // row contribution from tid (plus p*32)
    const int st_cb = tid & 7;           // 16B chunk within row

    for (int kt = 0; kt < 4; ++kt) {
        const int k0 = kt * 64;
        #pragma unroll
        for (int p = 0; p < 4; ++p) {
            const int chunk = p * 256 + tid;           // 0..1023, 16B each
            const int r = p * 32 + st_r;
            const int cb = st_cb ^ (r & 7);            // pre-swizzled global source
            const _Float16* ga = X16 + (size_t)(row0 + r) * DD + k0 + cb * 8;
            const _Float16* gb = X16 + (size_t)(col0 + r) * DD + k0 + cb * 8;
            __builtin_amdgcn_global_load_lds(
                (const __attribute__((address_space(1))) uint32_t*)ga,
                (__attribute__((address_space(3))) uint32_t*)&As[chunk * 8], 16, 0, 0);
            __builtin_amdgcn_global_load_lds(
                (const __attribute__((address_space(1))) uint32_t*)gb,
                (__attribute__((address_space(3))) uint32_t*)&Bs[chunk * 8], 16, 0, 0);
        }
        __syncthreads();
        #pragma unroll
        for (int ks = 0; ks < 64; ks += 32) {
            // swizzled k-offset (halves): chunk index (ks/8 + hi) ^ (row&7), x8
            const int kofs = ((((ks >> 3) + hi) ^ swz) << 3);
            half8 a[4], b[4];
            #pragma unroll
            for (int m = 0; m < 4; ++m)
                a[m] = *(const half8*)&As[(wr + m * 16 + rA) * 64 + kofs];
            #pragma unroll
            for (int n = 0; n < 4; ++n)
                b[n] = *(const half8*)&Bs[(wc + n * 16 + rA) * 64 + kofs];
            #pragma unroll
            for (int m = 0; m < 4; ++m)
                #pragma unroll
                for (int n = 0; n < 4; ++n)
                    acc[m][n] = __builtin_amdgcn_mfma_f32_16x16x32_f16(
                        a[m], b[n], acc[m][n], 0, 0, 0);
        }
        __syncthreads();
    }

    // epilogue: d2 -> 5-bandwidth kernel sum via e4 = exp2(-d2*cl2), powers 1,2,4,8,16
    const float cl2 = scal[0];
    const int c_lo = lane & 15, r_hi = lane >> 4;
    float sj[4], si[4][4];
    #pragma unroll
    for (int n = 0; n < 4; ++n) sj[n] = sq[col0 + wc + n * 16 + c_lo];
    #pragma unroll
    for (int m = 0; m < 4; ++m)
        #pragma unroll
        for (int r = 0; r < 4; ++r) si[m][r] = sq[row0 + wr + m * 16 + r_hi * 4 + r];

    float part = 0.0f;
    #pragma unroll
    for (int m = 0; m < 4; ++m)
        #pragma unroll
        for (int n = 0; n < 4; ++n)
            #pragma unroll
            for (int r = 0; r < 4; ++r) {
                const float g = acc[m][n][r];
                const float d2v = fmaxf(si[m][r] + sj[n] - 2.0f * g, 0.0f);
                float e = exp2f(-d2v * cl2);
                float ksum = e;
                e *= e; ksum += e;   // ^2
                e *= e; ksum += e;   // ^4
                e *= e; ksum += e;   // ^8
                e *= e; ksum += e;   // ^16
                part += ksum;
            }

    #pragma unroll
    for (int off = 32; off > 0; off >>= 1) part += __shfl_down(part, off);
    __shared__ float wsum[4];
    if (lane == 0) wsum[w] = part;
    __syncthreads();
    if (tid == 0)
        blockpart[bid] = (wsum[0] + wsum[1] + wsum[2] + wsum[3]) * wfac;
}

// ---------------------------------------------------------------- K4: final reduce
__global__ __launch_bounds__(256) void mmd_final(const float* __restrict__ blockpart,
                                                 float* __restrict__ out) {
    const int t = threadIdx.x;
    double acc = 0.0;
    for (int i = t; i < NBLK; i += 256) acc += (double)blockpart[i];
    #pragma unroll
    for (int off = 32; off > 0; off >>= 1) acc += __shfl_down(acc, off);
    __shared__ double sd[4];
    const int lane = t & 63, w = t >> 6;
    if (lane == 0) sd[w] = acc;
    __syncthreads();
    if (t == 0) {
        const double tot = (sd[0] + sd[1] + sd[2] + sd[3]) /
                           ((double)NS * (double)NS);
        out[0] = (float)fmax(tot, 0.0);
    }
}

// ---------------------------------------------------------------- launch
extern "C" void kernel_launch(void* const* d_in, const int* in_sizes, int n_in,
                              void* d_out, int out_size, void* d_ws, size_t ws_size,
                              hipStream_t stream) {
    const float* S = (const float*)d_in[0];
    const float* T = (const float*)d_in[1];
    char* ws = (char*)d_ws;
    _Float16* X16   = (_Float16*)(ws + OFF_X16);
    float* sq       = (float*)(ws + OFF_SQ);
    float* colpart  = (float*)(ws + OFF_COLP);
    float* blockpart= (float*)(ws + OFF_BP);
    float* scal     = (float*)(ws + OFF_SCAL);

    mmd_prep<<<256, 256, 0, stream>>>(S, T, X16, sq, colpart);
    mmd_bw<<<1, 256, 0, stream>>>(colpart, sq, scal);
    mmd_main<<<NBLK, 256, 0, stream>>>(X16, sq, scal, blockpart);
    mmd_final<<<1, 256, 0, stream>>>(blockpart, (float*)d_out);
}

// Round 4
// 66.661 us; speedup vs baseline: 1.5052x; 1.0465x over previous
//
#include <hip/hip_runtime.h>
#include <stdint.h>

typedef _Float16 half4 __attribute__((ext_vector_type(4)));
typedef _Float16 half8 __attribute__((ext_vector_type(8)));
typedef float f32x4 __attribute__((ext_vector_type(4)));

#define NS 4096
#define NTOT 8192
#define DD 256
#define NBLK 2080   // 528 SS lower-tri + 528 TT lower-tri + 1024 ST full
#define BK 32       // K-step; 8 K-tiles of 32 over K=256

// workspace layout (bytes)
#define OFF_X16   0                        // 8192*256*2 = 4 MB fp16
#define OFF_SQ    (4*1024*1024)            // 8192 floats
#define OFF_COLP  (OFF_SQ + 32*1024)       // 256*256 floats = 256 KB
#define OFF_BP    (OFF_COLP + 256*1024)    // 2080 floats
#define OFF_SCAL  (OFF_BP + 2080*4)        // 1 float (exp2 scale)

// ---------------------------------------------------------------- K1: prep
// 256 blocks x 256 threads (4 waves); block b handles rows [32b, 32b+32),
// one row per wave per iter; lane owns 4 contiguous cols (f32x4 / half4).
__global__ __launch_bounds__(256) void mmd_prep(const float* __restrict__ S,
                                                const float* __restrict__ T,
                                                _Float16* __restrict__ X16,
                                                float* __restrict__ sq,
                                                float* __restrict__ colpart) {
    __shared__ float cl[4][256];
    const int b = blockIdx.x, tid = threadIdx.x;
    const int lane = tid & 63, w = tid >> 6;
    f32x4 cacc = {0.f, 0.f, 0.f, 0.f};
    #pragma unroll
    for (int it = 0; it < 8; ++it) {
        const int row = b * 32 + it * 4 + w;     // wave-uniform row
        const float* src = (row < NS) ? (S + (size_t)row * DD)
                                      : (T + (size_t)(row - NS) * DD);
        const f32x4 v = *(const f32x4*)(src + lane * 4);
        cacc += v;
        float vv = v.x * v.x + v.y * v.y + v.z * v.z + v.w * v.w;
        half4 h = { (_Float16)v.x, (_Float16)v.y, (_Float16)v.z, (_Float16)v.w };
        *(half4*)(X16 + (size_t)row * DD + lane * 4) = h;
        #pragma unroll
        for (int off = 32; off; off >>= 1) vv += __shfl_down(vv, off);
        if (lane == 0) sq[row] = vv;
    }
    *(f32x4*)&cl[w][lane * 4] = cacc;
    __syncthreads();
    colpart[b * 256 + tid] = cl[0][tid] + cl[1][tid] + cl[2][tid] + cl[3][tid];
}

// ---------------------------------------------------------------- K2: bandwidth
// 1 block, 512 threads. sum(d2) = 2*n*sum(sq) - 2*||colsum||^2 (clamp negligible).
__global__ __launch_bounds__(512) void mmd_bw(const float* __restrict__ colpart,
                                              const float* __restrict__ sq,
                                              float* __restrict__ scal) {
    __shared__ float csh[256];
    __shared__ double sd[8], sf[8];
    const int t = threadIdx.x;
    const int hf = t >> 8, c = t & 255;
    float cs = 0.0f;
    #pragma unroll 4
    for (int b = 0; b < 128; ++b) cs += colpart[(hf * 128 + b) * 256 + c];
    if (hf) csh[c] = cs;
    __syncthreads();
    double s2 = 0.0;
    if (!hf) { const double tot = (double)cs + (double)csh[c]; s2 = tot * tot; }
    float qs = 0.0f;
    #pragma unroll
    for (int k = 0; k < 16; ++k) qs += sq[t + 512 * k];
    double qd = (double)qs;
    const int lane = t & 63, w = t >> 6;
    #pragma unroll
    for (int off = 32; off; off >>= 1) {
        s2 += __shfl_down(s2, off);
        qd += __shfl_down(qd, off);
    }
    if (lane == 0) { sd[w] = s2; sf[w] = qd; }
    __syncthreads();
    if (t == 0) {
        double s2t = 0.0, qt = 0.0;
        #pragma unroll
        for (int i = 0; i < 8; ++i) { s2t += sd[i]; qt += sf[i]; }
        const double n = (double)NTOT;
        const double sumd2 = 2.0 * n * qt - 2.0 * s2t;
        double bwv = sumd2 / (n * n - n);
        bwv = bwv / 4.0;   // KERNEL_MUL^(KERNEL_NUM//2) = 2^2
        // e4 = exp(-d2/(16*bw)) = exp2(-d2 * cl2)
        scal[0] = (float)(1.0 / (16.0 * bwv * 0.6931471805599453));
    }
}

// ---------------------------------------------------------------- K3: main GEMM+kernel
// 128x128 tile, BK=32, double-buffered LDS, T3 2-phase prefetch:
// STAGE(t+1) issued BEFORE COMPUTE(t); single barrier per K-step whose
// implicit drain lands after the MFMA cluster. T2 swizzle (linear
// global_load_lds dest + pre-swizzled source + swizzled ds_read),
// T5 setprio around MFMA, T1 XCD-aware bid swizzle. Fused exp epilogue.
__global__ __launch_bounds__(256) void mmd_main(const _Float16* __restrict__ X16,
                                                const float* __restrict__ sq,
                                                const float* __restrict__ scal,
                                                float* __restrict__ blockpart) {
    __shared__ _Float16 As[2][128 * BK];
    __shared__ _Float16 Bs[2][128 * BK];

    // T1: XCD swizzle (2080 % 8 == 0 -> bijective simple form)
    const int bid = (blockIdx.x % 8) * (NBLK / 8) + blockIdx.x / 8;
    int br, bc;
    float wfac;
    if (bid < 1056) {
        int t = bid, base = 0;
        if (t >= 528) { t -= 528; base = 32; }
        int i = (int)((sqrtf(8.0f * (float)t + 1.0f) - 1.0f) * 0.5f);
        while ((i + 1) * (i + 2) / 2 <= t) ++i;
        while (i * (i + 1) / 2 > t) --i;
        const int j = t - i * (i + 1) / 2;
        br = base + i; bc = base + j;
        wfac = (i == j) ? 1.0f : 2.0f;   // off-diag tile counts for (i,j) and (j,i)
    } else {
        const int t = bid - 1056;
        br = t >> 5; bc = 32 + (t & 31);
        wfac = -2.0f;                    // loss has -2*xy
    }
    const int row0 = br * 128, col0 = bc * 128;
    const int tid = threadIdx.x;
    const int lane = tid & 63;
    const int w = tid >> 6;
    const int wr = (w >> 1) * 64, wc = (w & 1) * 64;

    f32x4 acc[4][4] = {};

    const int rA = lane & 15;
    const int hi = lane >> 4;                      // k-chunk select (0..3)
    const int kofs = ((hi ^ (rA & 3)) << 3);       // swizzled, loop-invariant
    const int st_r  = tid >> 2;                    // staging row piece (0..63)
    const int st_cb = tid & 3;                     // staging 16B chunk in row

    // stage one 128x32 A-tile + B-tile pair into slot s (4 loads/thread)
    auto STAGE = [&](int s, int kt) {
        const int k0 = kt * BK;
        #pragma unroll
        for (int p = 0; p < 2; ++p) {
            const int chunk = p * 256 + tid;       // 0..511, 16B each
            const int r = p * 64 + st_r;           // 0..127
            const int cb = st_cb ^ (r & 3);        // pre-swizzled global source
            const _Float16* ga = X16 + (size_t)(row0 + r) * DD + k0 + cb * 8;
            const _Float16* gb = X16 + (size_t)(col0 + r) * DD + k0 + cb * 8;
            __builtin_amdgcn_global_load_lds(
                (const __attribute__((address_space(1))) uint32_t*)ga,
                (__attribute__((address_space(3))) uint32_t*)&As[s][chunk * 8], 16, 0, 0);
            __builtin_amdgcn_global_load_lds(
                (const __attribute__((address_space(1))) uint32_t*)gb,
                (__attribute__((address_space(3))) uint32_t*)&Bs[s][chunk * 8], 16, 0, 0);
        }
    };

    auto COMPUTE = [&](int s) {
        half8 a[4], b[4];
        #pragma unroll
        for (int m = 0; m < 4; ++m)
            a[m] = *(const half8*)&As[s][(wr + m * 16 + rA) * BK + kofs];
        #pragma unroll
        for (int n = 0; n < 4; ++n)
            b[n] = *(const half8*)&Bs[s][(wc + n * 16 + rA) * BK + kofs];
        __builtin_amdgcn_s_setprio(1);
        #pragma unroll
        for (int m = 0; m < 4; ++m)
            #pragma unroll
            for (int n = 0; n < 4; ++n)
                acc[m][n] = __builtin_amdgcn_mfma_f32_16x16x32_f16(
                    a[m], b[n], acc[m][n], 0, 0, 0);
        __builtin_amdgcn_s_setprio(0);
    };

    STAGE(0, 0);
    __syncthreads();                 // drains prologue stage
    #pragma unroll
    for (int kt = 0; kt < 7; ++kt) {
        STAGE((kt + 1) & 1, kt + 1); // prefetch next tile (other slot)
        COMPUTE(kt & 1);             // ds_read + MFMA current tile
        __syncthreads();             // drain: loads had whole MFMA phase to land
    }
    COMPUTE(1);                      // tile 7 (7&1 == 1), no prefetch

    // epilogue: d2 -> 5-bandwidth kernel sum via e4 = exp2(-d2*cl2), powers 1,2,4,8,16
    const float cl2 = scal[0];
    const int c_lo = lane & 15, r_hi = lane >> 4;
    float sj[4], si[4][4];
    #pragma unroll
    for (int n = 0; n < 4; ++n) sj[n] = sq[col0 + wc + n * 16 + c_lo];
    #pragma unroll
    for (int m = 0; m < 4; ++m)
        #pragma unroll
        for (int r = 0; r < 4; ++r) si[m][r] = sq[row0 + wr + m * 16 + r_hi * 4 + r];

    float part = 0.0f;
    #pragma unroll
    for (int m = 0; m < 4; ++m)
        #pragma unroll
        for (int n = 0; n < 4; ++n)
            #pragma unroll
            for (int r = 0; r < 4; ++r) {
                const float g = acc[m][n][r];
                const float d2v = fmaxf(si[m][r] + sj[n] - 2.0f * g, 0.0f);
                float e = exp2f(-d2v * cl2);
                float ksum = e;
                e *= e; ksum += e;   // ^2
                e *= e; ksum += e;   // ^4
                e *= e; ksum += e;   // ^8
                e *= e; ksum += e;   // ^16
                part += ksum;
            }

    #pragma unroll
    for (int off = 32; off > 0; off >>= 1) part += __shfl_down(part, off);
    __shared__ float wsum[4];
    if (lane == 0) wsum[w] = part;
    __syncthreads();
    if (tid == 0)
        blockpart[bid] = (wsum[0] + wsum[1] + wsum[2] + wsum[3]) * wfac;
}

// ---------------------------------------------------------------- K4: final reduce
__global__ __launch_bounds__(256) void mmd_final(const float* __restrict__ blockpart,
                                                 float* __restrict__ out) {
    const int t = threadIdx.x;
    double acc = 0.0;
    for (int i = t; i < NBLK; i += 256) acc += (double)blockpart[i];
    #pragma unroll
    for (int off = 32; off > 0; off >>= 1) acc += __shfl_down(acc, off);
    __shared__ double sd[4];
    const int lane = t & 63, w = t >> 6;
    if (lane == 0) sd[w] = acc;
    __syncthreads();
    if (t == 0) {
        const double tot = (sd[0] + sd[1] + sd[2] + sd[3]) /
                           ((double)NS * (double)NS);
        out[0] = (float)fmax(tot, 0.0);
    }
}

// ---------------------------------------------------------------- launch
extern "C" void kernel_launch(void* const* d_in, const int* in_sizes, int n_in,
                              void* d_out, int out_size, void* d_ws, size_t ws_size,
                              hipStream_t stream) {
    const float* S = (const float*)d_in[0];
    const float* T = (const float*)d_in[1];
    char* ws = (char*)d_ws;
    _Float16* X16   = (_Float16*)(ws + OFF_X16);
    float* sq       = (float*)(ws + OFF_SQ);
    float* colpart  = (float*)(ws + OFF_COLP);
    float* blockpart= (float*)(ws + OFF_BP);
    float* scal     = (float*)(ws + OFF_SCAL);

    mmd_prep<<<256, 256, 0, stream>>>(S, T, X16, sq, colpart);
    mmd_bw<<<1, 512, 0, stream>>>(colpart, sq, scal);
    mmd_main<<<NBLK, 256, 0, stream>>>(X16, sq, scal, blockpart);
    mmd_final<<<1, 256, 0, stream>>>(blockpart, (float*)d_out);
}